// Round 1
// baseline (521.599 us; speedup 1.0000x reference)
//
#include <hip/hip_runtime.h>
#include <hip/hip_bf16.h>
#include <cstdint>

typedef unsigned short u16;
typedef __attribute__((ext_vector_type(8))) u16 u16x8;
typedef __attribute__((ext_vector_type(4))) u16 u16x4;
typedef __attribute__((ext_vector_type(8))) __bf16 bf16x8;
typedef __attribute__((ext_vector_type(4))) float f32x4;

#define B_    8
#define T_    3137
#define H_    12
#define DH_   64
#define F_    16
#define P_    196
#define D_    768
#define M1    25096      /* B_*T_ */
#define MPAD  25216      /* 197*128 */
#define VSTR  3200       /* padded Vt row stride (keeps 8B alignment) */
#define LDK   40         /* padded LDS K stride: 40 shorts = 80B -> <=2-way bank conflict */

__device__ __forceinline__ u16 f2bf(float f) {
  unsigned u = __float_as_uint(f);
  return (u16)((u + 0x7FFFu + ((u >> 16) & 1u)) >> 16);
}
__device__ __forceinline__ float b2f(u16 v) {
  return __uint_as_float(((unsigned)v) << 16);
}

// ---------------- convert x (fp32) -> bf16 ----------------
__global__ __launch_bounds__(256) void k_cvt_x(const float* __restrict__ x,
                                               u16* __restrict__ xb, int n4) {
  int i = blockIdx.x * 256 + threadIdx.x;
  if (i >= n4) return;
  float4 v = ((const float4*)x)[i];
  u16x4 o = { f2bf(v.x), f2bf(v.y), f2bf(v.z), f2bf(v.w) };
  *(u16x4*)(xb + (size_t)i * 4) = o;
}

// ---------------- transpose fp32 RxC -> bf16 CxR (optional qkv column permutation) ----------------
__global__ __launch_bounds__(256) void k_transpose(const float* __restrict__ in,
                                                   u16* __restrict__ out,
                                                   int R, int C, int qkvperm) {
  __shared__ float tile[32][33];
  int c0 = blockIdx.x * 32, r0 = blockIdx.y * 32;
  int tx = threadIdx.x, ty = threadIdx.y;
  #pragma unroll
  for (int i = ty; i < 32; i += 8)
    tile[i][tx] = in[(size_t)(r0 + i) * C + c0 + tx];
  __syncthreads();
  #pragma unroll
  for (int i = ty; i < 32; i += 8) {
    int c = c0 + i;
    int orow;
    if (qkvperm) {
      int d = c / 36, rem = c - d * 36;
      int comp = rem / 12, hh = rem - comp * 12;
      orow = comp * 768 + hh * 64 + d;   // output col order: [comp][head][dim]
    } else {
      orow = c;
    }
    out[(size_t)orow * R + r0 + tx] = f2bf(tile[tx][i]);
  }
}

// ---------------- 128x128x(K=768) bf16 MFMA GEMM, reg-staged LDS ----------------
// EPI==0: plain fp32 store to outF (GEMM2).  EPI==1: scatter to Qb/Kb/Vt (GEMM1).
template<int EPI>
__global__ __launch_bounds__(256) void k_gemm(const u16* __restrict__ A,
                                              const u16* __restrict__ Bm,
                                              float* __restrict__ outF,
                                              u16* __restrict__ Qb,
                                              u16* __restrict__ Kb,
                                              u16* __restrict__ Vt) {
  __shared__ u16 As[128 * LDK];
  __shared__ u16 Bs[128 * LDK];
  const int tid = threadIdx.x;
  const int lane = tid & 63;
  const int wid = tid >> 6;
  const int wr = wid >> 1, wc = wid & 1;
  const int li = lane & 15, lg = lane >> 4;
  const size_t arow0 = (size_t)blockIdx.y * 128;
  const size_t brow0 = (size_t)blockIdx.x * 128;

  f32x4 acc[4][4] = {};
  const int r0s = tid >> 2;
  const int kcs = (tid & 3) * 8;

  for (int kt = 0; kt < 24; ++kt) {
    const int kb = kt * 32;
    __syncthreads();
    #pragma unroll
    for (int j = 0; j < 2; ++j) {
      int r = j * 64 + r0s;
      u16x8 av = *(const u16x8*)(A  + (arow0 + r) * 768 + kb + kcs);
      u16x8 bv = *(const u16x8*)(Bm + (brow0 + r) * 768 + kb + kcs);
      *(u16x8*)(As + r * LDK + kcs) = av;
      *(u16x8*)(Bs + r * LDK + kcs) = bv;
    }
    __syncthreads();
    bf16x8 af[4], bfr[4];
    #pragma unroll
    for (int m = 0; m < 4; ++m)
      af[m] = *(const bf16x8*)(As + (wr * 64 + m * 16 + li) * LDK + lg * 8);
    #pragma unroll
    for (int n = 0; n < 4; ++n)
      bfr[n] = *(const bf16x8*)(Bs + (wc * 64 + n * 16 + li) * LDK + lg * 8);
    #pragma unroll
    for (int m = 0; m < 4; ++m)
      #pragma unroll
      for (int n = 0; n < 4; ++n)
        acc[m][n] = __builtin_amdgcn_mfma_f32_16x16x32_bf16(af[m], bfr[n], acc[m][n], 0, 0, 0);
  }

  #pragma unroll
  for (int m = 0; m < 4; ++m) {
    #pragma unroll
    for (int n = 0; n < 4; ++n) {
      const int colp = (int)brow0 + wc * 64 + n * 16 + li;
      #pragma unroll
      for (int r = 0; r < 4; ++r) {
        size_t row = arow0 + wr * 64 + m * 16 + lg * 4 + r;
        if (row >= M1) continue;
        float val = acc[m][n][r];
        if (EPI == 0) {
          outF[row * 768 + colp] = val;
        } else {
          // colp ordered [comp][head][dim] thanks to permuted W_qkv^T
          const int comp = colp / 768;
          const int rem = colp - comp * 768;
          const int hh = rem >> 6, dd = rem & 63;
          const int b = (int)(row / T_);
          const int t = (int)(row - (size_t)b * T_);
          const u16 v = f2bf(val);
          const size_t bh = (size_t)b * H_ + hh;
          if (comp == 0)      Qb[(bh * T_ + t) * 64 + dd] = v;
          else if (comp == 1) Kb[(bh * T_ + t) * 64 + dd] = v;
          else                Vt[(bh * 64 + dd) * VSTR + t] = v;
        }
      }
    }
  }
}

// ---------------- spatial attention: one block per (b,f,h), 4 waves ----------------
// keys: 0 = cls token (t=0), j in [1,196] -> t = f*196 + j. Padded key space = 224.
__global__ __launch_bounds__(256) void k_attn_sp(const u16* __restrict__ Qb,
                                                 const u16* __restrict__ Kb,
                                                 const u16* __restrict__ Vt,
                                                 u16* __restrict__ AO) {
  __shared__ u16 P[4][16 * 232];   // per-wave P tile, padded stride 232
  const int bid = blockIdx.x;
  const int h = bid % H_;
  const int f = (bid / H_) % F_;
  const int b = bid / (H_ * F_);
  const int tid = threadIdx.x;
  const int lane = tid & 63, w = tid >> 6;
  const int li = lane & 15, lg = lane >> 4;
  const size_t bh = (size_t)b * H_ + h;
  const u16* Qp = Qb + bh * T_ * 64;
  const u16* Kp = Kb + bh * T_ * 64;
  const u16* Vp = Vt + bh * 64 * VSTR;
  u16* ps = &P[w][0];

  for (int mt = w; mt < 13; mt += 4) {          // 13 m-tiles of 16 q-rows (196 valid)
    const int pp = mt * 16 + li;
    const int ppc = pp < 196 ? pp : 195;
    const size_t tq = 1 + f * 196 + ppc;
    const bf16x8 qf0 = *(const bf16x8*)(Qp + tq * 64 + lg * 8);
    const bf16x8 qf1 = *(const bf16x8*)(Qp + tq * 64 + 32 + lg * 8);

    f32x4 s[14] = {};
    #pragma unroll
    for (int n = 0; n < 14; ++n) {
      const int key = n * 16 + li;
      int tk = (key == 0) ? 0 : (f * 196 + key);
      if (tk > 3136) tk = 3136;                 // pad keys: garbage, masked below
      const u16* kp = Kp + (size_t)tk * 64;
      const bf16x8 kf0 = *(const bf16x8*)(kp + lg * 8);
      const bf16x8 kf1 = *(const bf16x8*)(kp + 32 + lg * 8);
      s[n] = __builtin_amdgcn_mfma_f32_16x16x32_bf16(qf0, kf0, s[n], 0, 0, 0);
      s[n] = __builtin_amdgcn_mfma_f32_16x16x32_bf16(qf1, kf1, s[n], 0, 0, 0);
    }

    float rsum[4];
    #pragma unroll
    for (int r = 0; r < 4; ++r) {
      float vals[14];
      float mx = -1e30f;
      #pragma unroll
      for (int n = 0; n < 14; ++n) {
        const int key = n * 16 + li;
        float sv = s[n][r] * 0.125f;
        vals[n] = (key < 197) ? sv : -1e30f;
        mx = fmaxf(mx, vals[n]);
      }
      #pragma unroll
      for (int msk = 1; msk < 16; msk <<= 1) mx = fmaxf(mx, __shfl_xor(mx, msk));
      float sum = 0.f;
      #pragma unroll
      for (int n = 0; n < 14; ++n) {
        const int key = n * 16 + li;
        float p = (key < 197) ? __expf(vals[n] - mx) : 0.f;
        sum += p;
        ps[(lg * 4 + r) * 232 + key] = f2bf(p);
      }
      #pragma unroll
      for (int msk = 1; msk < 16; msk <<= 1) sum += __shfl_xor(sum, msk);
      rsum[r] = sum;
    }

    f32x4 o[4] = {};
    #pragma unroll
    for (int ks = 0; ks < 7; ++ks) {            // K = 224 padded keys
      const bf16x8 pf = *(const bf16x8*)(ps + li * 232 + ks * 32 + lg * 8);
      const int keyb = ks * 32 + lg * 8;
      #pragma unroll
      for (int n = 0; n < 4; ++n) {
        const int d = n * 16 + li;
        const u16* vp = Vp + (size_t)d * VSTR + f * 196 + keyb;  // 8B aligned
        u16x4 va = *(const u16x4*)vp;
        u16x4 vb2 = *(const u16x4*)(vp + 4);
        if (keyb == 0) va[0] = Vp[(size_t)d * VSTR];             // patch cls (t=0)
        u16x8 uv = { va[0], va[1], va[2], va[3], vb2[0], vb2[1], vb2[2], vb2[3] };
        const bf16x8 vf = __builtin_bit_cast(bf16x8, uv);
        o[n] = __builtin_amdgcn_mfma_f32_16x16x32_bf16(pf, vf, o[n], 0, 0, 0);
      }
    }

    #pragma unroll
    for (int n = 0; n < 4; ++n) {
      const int d = n * 16 + li;
      #pragma unroll
      for (int r = 0; r < 4; ++r) {
        const int ppo = mt * 16 + lg * 4 + r;
        if (ppo < 196) {
          const size_t t = 1 + (size_t)f * 196 + ppo;
          AO[((size_t)b * T_ + t) * 768 + h * 64 + d] = f2bf(o[n][r] / rsum[r]);
        }
      }
    }
  }
}

// ---------------- cls-token attention: one block per (b,h), full 3137-key softmax ----------------
__global__ __launch_bounds__(256) void k_attn_cls(const u16* __restrict__ Qb,
                                                  const u16* __restrict__ Kb,
                                                  const u16* __restrict__ Vt,
                                                  u16* __restrict__ AO) {
  __shared__ float qs[64];
  __shared__ float sv[T_];
  __shared__ float red[8];
  const int bid = blockIdx.x;
  const int h = bid % H_;
  const int b = bid / H_;
  const size_t bh = (size_t)b * H_ + h;
  const u16* Qp = Qb + bh * T_ * 64;
  const u16* Kp = Kb + bh * T_ * 64;
  const u16* Vp = Vt + bh * 64 * VSTR;
  const int tid = threadIdx.x;
  const int lane = tid & 63, w = tid >> 6;

  if (tid < 64) qs[tid] = b2f(Qp[tid]);
  __syncthreads();

  float lmax = -1e30f;
  for (int j = tid; j < T_; j += 256) {
    const u16* kp = Kp + (size_t)j * 64;
    float acc = 0.f;
    #pragma unroll
    for (int d0 = 0; d0 < 64; d0 += 8) {
      u16x8 kv = *(const u16x8*)(kp + d0);
      #pragma unroll
      for (int e = 0; e < 8; ++e) acc += qs[d0 + e] * b2f(kv[e]);
    }
    acc *= 0.125f;
    sv[j] = acc;
    lmax = fmaxf(lmax, acc);
  }
  #pragma unroll
  for (int msk = 32; msk; msk >>= 1) lmax = fmaxf(lmax, __shfl_xor(lmax, msk));
  if (lane == 0) red[w] = lmax;
  __syncthreads();
  const float bmax = fmaxf(fmaxf(red[0], red[1]), fmaxf(red[2], red[3]));

  float lsum = 0.f;
  for (int j = tid; j < T_; j += 256) {
    float p = __expf(sv[j] - bmax);
    sv[j] = p;
    lsum += p;
  }
  #pragma unroll
  for (int msk = 32; msk; msk >>= 1) lsum += __shfl_xor(lsum, msk);
  __syncthreads();
  if (lane == 0) red[w] = lsum;
  __syncthreads();
  const float bsum = red[0] + red[1] + red[2] + red[3];

  const int d = tid >> 2, q4 = tid & 3;
  const u16* vp = Vp + (size_t)d * VSTR;
  float a = 0.f;
  for (int j = q4; j < T_; j += 4) a += sv[j] * b2f(vp[j]);
  a += __shfl_xor(a, 1);
  a += __shfl_xor(a, 2);
  if (q4 == 0) AO[(size_t)b * T_ * 768 + h * 64 + d] = f2bf(a / bsum);
}

// ---------------- launch ----------------
extern "C" void kernel_launch(void* const* d_in, const int* in_sizes, int n_in,
                              void* d_out, int out_size, void* d_ws, size_t ws_size,
                              hipStream_t stream) {
  const float* x    = (const float*)d_in[0];
  const float* Wqkv = (const float*)d_in[1];
  const float* W0   = (const float*)d_in[2];
  float* out = (float*)d_out;
  char* ws = (char*)d_ws;

  // workspace layout (bytes)
  u16* xb    = (u16*)(ws);                  // MPAD*768*2      = 38,731,776 ; later reused as AO
  u16* wqkvT = (u16*)(ws + 38731776);       // 2304*768*2      =  3,538,944
  u16* w0T   = (u16*)(ws + 42270720);       // 768*768*2       =  1,179,648
  u16* Qb    = (u16*)(ws + 43450368);       // 96*3137*64*2    = 38,547,456
  u16* Kb    = (u16*)(ws + 81997824);       // same
  u16* Vt    = (u16*)(ws + 120545280);      // 96*64*3200*2    = 39,321,600  (end 159,866,880)
  u16* AO = xb;                             // xb is dead after GEMM1

  k_cvt_x<<<dim3(18822), dim3(256), 0, stream>>>(x, xb, (M1 * D_) / 4);
  k_transpose<<<dim3(72, 24), dim3(32, 8), 0, stream>>>(Wqkv, wqkvT, 768, 2304, 1);
  k_transpose<<<dim3(24, 24), dim3(32, 8), 0, stream>>>(W0, w0T, 768, 768, 0);
  k_gemm<1><<<dim3(18, 197), dim3(256), 0, stream>>>(xb, wqkvT, nullptr, Qb, Kb, Vt);
  k_attn_sp<<<dim3(1536), dim3(256), 0, stream>>>(Qb, Kb, Vt, AO);
  k_attn_cls<<<dim3(96), dim3(256), 0, stream>>>(Qb, Kb, Vt, AO);
  k_gemm<0><<<dim3(6, 197), dim3(256), 0, stream>>>(AO, w0T, out, nullptr, nullptr, nullptr);
}

// Round 2
// 490.449 us; speedup vs baseline: 1.0635x; 1.0635x over previous
//
#include <hip/hip_runtime.h>
#include <hip/hip_bf16.h>
#include <cstdint>

typedef unsigned short u16;
typedef __attribute__((ext_vector_type(8))) u16 u16x8;
typedef __attribute__((ext_vector_type(4))) u16 u16x4;
typedef __attribute__((ext_vector_type(8))) __bf16 bf16x8;
typedef __attribute__((ext_vector_type(4))) float f32x4;

#define B_    8
#define T_    3137
#define H_    12
#define DH_   64
#define F_    16
#define P_    196
#define D_    768
#define M1    25096      /* B_*T_ */
#define MPAD  25216      /* 197*128 */
#define VSTR  3200       /* padded Vt row stride (keeps 8B alignment) */

__device__ __forceinline__ u16 f2bf(float f) {
  unsigned u = __float_as_uint(f);
  return (u16)((u + 0x7FFFu + ((u >> 16) & 1u)) >> 16);
}
__device__ __forceinline__ float b2f(u16 v) {
  return __uint_as_float(((unsigned)v) << 16);
}

// global -> LDS direct DMA, 16B per lane; dest = wave-uniform base + lane*16
#define GLL(g, l) __builtin_amdgcn_global_load_lds( \
    (const __attribute__((address_space(1))) void*)(g), \
    (__attribute__((address_space(3))) void*)(l), 16, 0, 0)

// ---------------- convert x (fp32) -> bf16 ----------------
__global__ __launch_bounds__(256) void k_cvt_x(const float* __restrict__ x,
                                               u16* __restrict__ xb, int n4) {
  int i = blockIdx.x * 256 + threadIdx.x;
  if (i >= n4) return;
  float4 v = ((const float4*)x)[i];
  u16x4 o = { f2bf(v.x), f2bf(v.y), f2bf(v.z), f2bf(v.w) };
  *(u16x4*)(xb + (size_t)i * 4) = o;
}

// ---------------- transpose fp32 RxC -> bf16 CxR (optional qkv column permutation) ----------------
__global__ __launch_bounds__(256) void k_transpose(const float* __restrict__ in,
                                                   u16* __restrict__ out,
                                                   int R, int C, int qkvperm) {
  __shared__ float tile[32][33];
  int c0 = blockIdx.x * 32, r0 = blockIdx.y * 32;
  int tx = threadIdx.x, ty = threadIdx.y;
  #pragma unroll
  for (int i = ty; i < 32; i += 8)
    tile[i][tx] = in[(size_t)(r0 + i) * C + c0 + tx];
  __syncthreads();
  #pragma unroll
  for (int i = ty; i < 32; i += 8) {
    int c = c0 + i;
    int orow;
    if (qkvperm) {
      int d = c / 36, rem = c - d * 36;
      int comp = rem / 12, hh = rem - comp * 12;
      orow = comp * 768 + hh * 64 + d;   // output col order: [comp][head][dim]
    } else {
      orow = c;
    }
    out[(size_t)orow * R + r0 + tx] = f2bf(tile[tx][i]);
  }
}

// ---------------- 128x128x(K=768) bf16 MFMA GEMM, m97 structure ----------------
// global_load_lds width=16 staging into linear [128][32] LDS, 2 barriers/K-step.
// EPI==0: plain fp32 store to outF (GEMM2).  EPI==1: scatter to Qb/Kb/Vt (GEMM1).
template<int EPI>
__global__ __launch_bounds__(256) void k_gemm(const u16* __restrict__ A,
                                              const u16* __restrict__ Bm,
                                              float* __restrict__ outF,
                                              u16* __restrict__ Qb,
                                              u16* __restrict__ Kb,
                                              u16* __restrict__ Vt) {
  __shared__ u16 As[128 * 32];
  __shared__ u16 Bs[128 * 32];
  const int tid = threadIdx.x;
  const int lane = tid & 63;
  const int wid = tid >> 6;
  const int wr = wid >> 1, wc = wid & 1;
  const int li = lane & 15, lg = lane >> 4;
  const size_t arow0 = (size_t)blockIdx.y * 128;
  const size_t brow0 = (size_t)blockIdx.x * 128;

  // staging: wave `wid` fills rows [wid*32, wid*32+32) via two 1KB chunks.
  // lane i of a chunk sources row (base + i/4), cols (i%4)*8 .. +8
  const int srow = wid * 32 + (lane >> 2);
  const int scol = (lane & 3) * 8;
  const u16* gA = A  + (arow0 + srow) * 768 + scol;
  const u16* gB = Bm + (brow0 + srow) * 768 + scol;
  u16* lA = As + wid * 32 * 32;   // wave-uniform LDS base (byte = wid*2048)
  u16* lB = Bs + wid * 32 * 32;

  f32x4 acc[4][4] = {};

  for (int kt = 0; kt < 24; ++kt) {
    const int kb = kt * 32;
    GLL(gA + kb,            lA);
    GLL(gA + kb + 16 * 768, lA + 16 * 32);
    GLL(gB + kb,            lB);
    GLL(gB + kb + 16 * 768, lB + 16 * 32);
    __syncthreads();                       // compiler drains vmcnt(0) before barrier
    bf16x8 af[4], bfr[4];
    #pragma unroll
    for (int m = 0; m < 4; ++m)
      af[m] = *(const bf16x8*)(As + (wr * 64 + m * 16 + li) * 32 + lg * 8);
    #pragma unroll
    for (int n = 0; n < 4; ++n)
      bfr[n] = *(const bf16x8*)(Bs + (wc * 64 + n * 16 + li) * 32 + lg * 8);
    #pragma unroll
    for (int m = 0; m < 4; ++m)
      #pragma unroll
      for (int n = 0; n < 4; ++n)
        acc[m][n] = __builtin_amdgcn_mfma_f32_16x16x32_bf16(af[m], bfr[n], acc[m][n], 0, 0, 0);
    __syncthreads();                       // all ds_reads done -> safe to overwrite LDS
  }

  #pragma unroll
  for (int m = 0; m < 4; ++m) {
    #pragma unroll
    for (int n = 0; n < 4; ++n) {
      const int colp = (int)brow0 + wc * 64 + n * 16 + li;
      #pragma unroll
      for (int r = 0; r < 4; ++r) {
        size_t row = arow0 + wr * 64 + m * 16 + lg * 4 + r;
        if (row >= M1) continue;
        float val = acc[m][n][r];
        if (EPI == 0) {
          outF[row * 768 + colp] = val;
        } else {
          // colp ordered [comp][head][dim] thanks to permuted W_qkv^T
          const int comp = colp / 768;
          const int rem = colp - comp * 768;
          const int hh = rem >> 6, dd = rem & 63;
          const int b = (int)(row / T_);
          const int t = (int)(row - (size_t)b * T_);
          const u16 v = f2bf(val);
          const size_t bh = (size_t)b * H_ + hh;
          if (comp == 0)      Qb[(bh * T_ + t) * 64 + dd] = v;
          else if (comp == 1) Kb[(bh * T_ + t) * 64 + dd] = v;
          else                Vt[(bh * 64 + dd) * VSTR + t] = v;
        }
      }
    }
  }
}

// ---------------- spatial attention: one block per (b,f,h), 4 waves ----------------
// keys: 0 = cls token (t=0), j in [1,196] -> t = f*196 + j. Padded key space = 224.
__global__ __launch_bounds__(256) void k_attn_sp(const u16* __restrict__ Qb,
                                                 const u16* __restrict__ Kb,
                                                 const u16* __restrict__ Vt,
                                                 u16* __restrict__ AO) {
  __shared__ u16 P[4][16 * 232];   // per-wave P tile, padded stride 232
  const int bid = blockIdx.x;
  const int h = bid % H_;
  const int f = (bid / H_) % F_;
  const int b = bid / (H_ * F_);
  const int tid = threadIdx.x;
  const int lane = tid & 63, w = tid >> 6;
  const int li = lane & 15, lg = lane >> 4;
  const size_t bh = (size_t)b * H_ + h;
  const u16* Qp = Qb + bh * T_ * 64;
  const u16* Kp = Kb + bh * T_ * 64;
  const u16* Vp = Vt + bh * 64 * VSTR;
  u16* ps = &P[w][0];

  for (int mt = w; mt < 13; mt += 4) {          // 13 m-tiles of 16 q-rows (196 valid)
    const int pp = mt * 16 + li;
    const int ppc = pp < 196 ? pp : 195;
    const size_t tq = 1 + f * 196 + ppc;
    const bf16x8 qf0 = *(const bf16x8*)(Qp + tq * 64 + lg * 8);
    const bf16x8 qf1 = *(const bf16x8*)(Qp + tq * 64 + 32 + lg * 8);

    f32x4 s[14] = {};
    #pragma unroll
    for (int n = 0; n < 14; ++n) {
      const int key = n * 16 + li;
      int tk = (key == 0) ? 0 : (f * 196 + key);
      if (tk > 3136) tk = 3136;                 // pad keys: garbage, masked below
      const u16* kp = Kp + (size_t)tk * 64;
      const bf16x8 kf0 = *(const bf16x8*)(kp + lg * 8);
      const bf16x8 kf1 = *(const bf16x8*)(kp + 32 + lg * 8);
      s[n] = __builtin_amdgcn_mfma_f32_16x16x32_bf16(qf0, kf0, s[n], 0, 0, 0);
      s[n] = __builtin_amdgcn_mfma_f32_16x16x32_bf16(qf1, kf1, s[n], 0, 0, 0);
    }

    float rsum[4];
    #pragma unroll
    for (int r = 0; r < 4; ++r) {
      float vals[14];
      float mx = -1e30f;
      #pragma unroll
      for (int n = 0; n < 14; ++n) {
        const int key = n * 16 + li;
        float sv = s[n][r] * 0.125f;
        vals[n] = (key < 197) ? sv : -1e30f;
        mx = fmaxf(mx, vals[n]);
      }
      #pragma unroll
      for (int msk = 1; msk < 16; msk <<= 1) mx = fmaxf(mx, __shfl_xor(mx, msk));
      float sum = 0.f;
      #pragma unroll
      for (int n = 0; n < 14; ++n) {
        const int key = n * 16 + li;
        float p = (key < 197) ? __expf(vals[n] - mx) : 0.f;
        sum += p;
        ps[(lg * 4 + r) * 232 + key] = f2bf(p);
      }
      #pragma unroll
      for (int msk = 1; msk < 16; msk <<= 1) sum += __shfl_xor(sum, msk);
      rsum[r] = sum;
    }

    f32x4 o[4] = {};
    #pragma unroll
    for (int ks = 0; ks < 7; ++ks) {            // K = 224 padded keys
      const bf16x8 pf = *(const bf16x8*)(ps + li * 232 + ks * 32 + lg * 8);
      const int keyb = ks * 32 + lg * 8;
      #pragma unroll
      for (int n = 0; n < 4; ++n) {
        const int d = n * 16 + li;
        const u16* vp = Vp + (size_t)d * VSTR + f * 196 + keyb;  // 8B aligned
        u16x4 va = *(const u16x4*)vp;
        u16x4 vb2 = *(const u16x4*)(vp + 4);
        if (keyb == 0) va[0] = Vp[(size_t)d * VSTR];             // patch cls (t=0)
        u16x8 uv = { va[0], va[1], va[2], va[3], vb2[0], vb2[1], vb2[2], vb2[3] };
        const bf16x8 vf = __builtin_bit_cast(bf16x8, uv);
        o[n] = __builtin_amdgcn_mfma_f32_16x16x32_bf16(pf, vf, o[n], 0, 0, 0);
      }
    }

    #pragma unroll
    for (int n = 0; n < 4; ++n) {
      const int d = n * 16 + li;
      #pragma unroll
      for (int r = 0; r < 4; ++r) {
        const int ppo = mt * 16 + lg * 4 + r;
        if (ppo < 196) {
          const size_t t = 1 + (size_t)f * 196 + ppo;
          AO[((size_t)b * T_ + t) * 768 + h * 64 + d] = f2bf(o[n][r] / rsum[r]);
        }
      }
    }
  }
}

// ---------------- cls-token attention: one block per (b,h), full 3137-key softmax ----------------
__global__ __launch_bounds__(256) void k_attn_cls(const u16* __restrict__ Qb,
                                                  const u16* __restrict__ Kb,
                                                  const u16* __restrict__ Vt,
                                                  u16* __restrict__ AO) {
  __shared__ float qs[64];
  __shared__ float sv[T_];
  __shared__ float red[8];
  const int bid = blockIdx.x;
  const int h = bid % H_;
  const int b = bid / H_;
  const size_t bh = (size_t)b * H_ + h;
  const u16* Qp = Qb + bh * T_ * 64;
  const u16* Kp = Kb + bh * T_ * 64;
  const u16* Vp = Vt + bh * 64 * VSTR;
  const int tid = threadIdx.x;
  const int lane = tid & 63, w = tid >> 6;

  if (tid < 64) qs[tid] = b2f(Qp[tid]);
  __syncthreads();

  float lmax = -1e30f;
  for (int j = tid; j < T_; j += 256) {
    const u16* kp = Kp + (size_t)j * 64;
    float acc = 0.f;
    #pragma unroll
    for (int d0 = 0; d0 < 64; d0 += 8) {
      u16x8 kv = *(const u16x8*)(kp + d0);
      #pragma unroll
      for (int e = 0; e < 8; ++e) acc += qs[d0 + e] * b2f(kv[e]);
    }
    acc *= 0.125f;
    sv[j] = acc;
    lmax = fmaxf(lmax, acc);
  }
  #pragma unroll
  for (int msk = 32; msk; msk >>= 1) lmax = fmaxf(lmax, __shfl_xor(lmax, msk));
  if (lane == 0) red[w] = lmax;
  __syncthreads();
  const float bmax = fmaxf(fmaxf(red[0], red[1]), fmaxf(red[2], red[3]));

  float lsum = 0.f;
  for (int j = tid; j < T_; j += 256) {
    float p = __expf(sv[j] - bmax);
    sv[j] = p;
    lsum += p;
  }
  #pragma unroll
  for (int msk = 32; msk; msk >>= 1) lsum += __shfl_xor(lsum, msk);
  __syncthreads();
  if (lane == 0) red[w] = lsum;
  __syncthreads();
  const float bsum = red[0] + red[1] + red[2] + red[3];

  const int d = tid >> 2, q4 = tid & 3;
  const u16* vp = Vp + (size_t)d * VSTR;
  float a = 0.f;
  for (int j = q4; j < T_; j += 4) a += sv[j] * b2f(vp[j]);
  a += __shfl_xor(a, 1);
  a += __shfl_xor(a, 2);
  if (q4 == 0) AO[(size_t)b * T_ * 768 + h * 64 + d] = f2bf(a / bsum);
}

// ---------------- launch ----------------
extern "C" void kernel_launch(void* const* d_in, const int* in_sizes, int n_in,
                              void* d_out, int out_size, void* d_ws, size_t ws_size,
                              hipStream_t stream) {
  const float* x    = (const float*)d_in[0];
  const float* Wqkv = (const float*)d_in[1];
  const float* W0   = (const float*)d_in[2];
  float* out = (float*)d_out;
  char* ws = (char*)d_ws;

  // workspace layout (bytes)
  u16* xb    = (u16*)(ws);                  // MPAD*768*2      = 38,731,776 ; later reused as AO
  u16* wqkvT = (u16*)(ws + 38731776);       // 2304*768*2      =  3,538,944
  u16* w0T   = (u16*)(ws + 42270720);       // 768*768*2       =  1,179,648
  u16* Qb    = (u16*)(ws + 43450368);       // 96*3137*64*2    = 38,547,456
  u16* Kb    = (u16*)(ws + 81997824);       // same
  u16* Vt    = (u16*)(ws + 120545280);      // 96*64*3200*2    = 39,321,600  (end 159,866,880)
  u16* AO = xb;                             // xb is dead after GEMM1

  k_cvt_x<<<dim3(18822), dim3(256), 0, stream>>>(x, xb, (M1 * D_) / 4);
  k_transpose<<<dim3(72, 24), dim3(32, 8), 0, stream>>>(Wqkv, wqkvT, 768, 2304, 1);
  k_transpose<<<dim3(24, 24), dim3(32, 8), 0, stream>>>(W0, w0T, 768, 768, 0);
  k_gemm<1><<<dim3(18, 197), dim3(256), 0, stream>>>(xb, wqkvT, nullptr, Qb, Kb, Vt);
  k_attn_sp<<<dim3(1536), dim3(256), 0, stream>>>(Qb, Kb, Vt, AO);
  k_attn_cls<<<dim3(96), dim3(256), 0, stream>>>(Qb, Kb, Vt, AO);
  k_gemm<0><<<dim3(6, 197), dim3(256), 0, stream>>>(AO, w0T, out, nullptr, nullptr, nullptr);
}

// Round 3
// 476.643 us; speedup vs baseline: 1.0943x; 1.0290x over previous
//
#include <hip/hip_runtime.h>
#include <hip/hip_bf16.h>
#include <cstdint>

typedef unsigned short u16;
typedef __attribute__((ext_vector_type(8))) u16 u16x8;
typedef __attribute__((ext_vector_type(4))) u16 u16x4;
typedef __attribute__((ext_vector_type(8))) __bf16 bf16x8;
typedef __attribute__((ext_vector_type(4))) float f32x4;

#define B_    8
#define T_    3137
#define H_    12
#define DH_   64
#define F_    16
#define P_    196
#define D_    768
#define M1    25096      /* B_*T_ */
#define MPAD  25216      /* 197*128 */
#define VSTR  3200       /* padded Vt row stride (keeps 8B alignment) */

__device__ __forceinline__ u16 f2bf(float f) {
  unsigned u = __float_as_uint(f);
  return (u16)((u + 0x7FFFu + ((u >> 16) & 1u)) >> 16);
}
__device__ __forceinline__ float b2f(u16 v) {
  return __uint_as_float(((unsigned)v) << 16);
}

// global -> LDS direct DMA, 16B per lane; dest = wave-uniform base + lane*16
#define GLL(g, l) __builtin_amdgcn_global_load_lds( \
    (const __attribute__((address_space(1))) void*)(g), \
    (__attribute__((address_space(3))) void*)(l), 16, 0, 0)

// ---------------- convert x (fp32) -> bf16 ----------------
__global__ __launch_bounds__(256) void k_cvt_x(const float* __restrict__ x,
                                               u16* __restrict__ xb, int n4) {
  int i = blockIdx.x * 256 + threadIdx.x;
  if (i >= n4) return;
  float4 v = ((const float4*)x)[i];
  u16x4 o = { f2bf(v.x), f2bf(v.y), f2bf(v.z), f2bf(v.w) };
  *(u16x4*)(xb + (size_t)i * 4) = o;
}

// ---------------- transpose fp32 RxC -> bf16 CxR (optional qkv column permutation) ----------------
__global__ __launch_bounds__(256) void k_transpose(const float* __restrict__ in,
                                                   u16* __restrict__ out,
                                                   int R, int C, int qkvperm) {
  __shared__ float tile[32][33];
  int c0 = blockIdx.x * 32, r0 = blockIdx.y * 32;
  int tx = threadIdx.x, ty = threadIdx.y;
  #pragma unroll
  for (int i = ty; i < 32; i += 8)
    tile[i][tx] = in[(size_t)(r0 + i) * C + c0 + tx];
  __syncthreads();
  #pragma unroll
  for (int i = ty; i < 32; i += 8) {
    int c = c0 + i;
    int orow;
    if (qkvperm) {
      int d = c / 36, rem = c - d * 36;
      int comp = rem / 12, hh = rem - comp * 12;
      orow = comp * 768 + hh * 64 + d;   // output col order: [comp][head][dim]
    } else {
      orow = c;
    }
    out[(size_t)orow * R + r0 + tx] = f2bf(tile[tx][i]);
  }
}

// ---------------- 128x128x(K=768) bf16 MFMA GEMM, 2-phase double-buffered ----------------
// T3-minimum schedule: prefetch next K-tile via global_load_lds BEFORE consuming
// current tile; one barrier per K-step (compiler drains vmcnt+lgkm at barrier).
// EPI==0: plain fp32 store to outF (GEMM2).  EPI==1: scatter to Qb/Kb/Vt (GEMM1).
template<int EPI>
__global__ __launch_bounds__(256) void k_gemm(const u16* __restrict__ A,
                                              const u16* __restrict__ Bm,
                                              float* __restrict__ outF,
                                              u16* __restrict__ Qb,
                                              u16* __restrict__ Kb,
                                              u16* __restrict__ Vt) {
  __shared__ u16 As0[128 * 32], Bs0[128 * 32];
  __shared__ u16 As1[128 * 32], Bs1[128 * 32];
  const int tid = threadIdx.x;
  const int lane = tid & 63;
  const int wid = tid >> 6;
  const int wr = wid >> 1, wc = wid & 1;
  const int li = lane & 15, lg = lane >> 4;
  const int arow0 = blockIdx.y * 128;
  const int brow0 = blockIdx.x * 128;

  // staging: wave `wid` fills rows [wid*32, wid*32+32); lane i -> row base+i/4, col (i%4)*8
  const int srow = wid * 32 + (lane >> 2);
  const int scol = (lane & 3) * 8;
  const u16* gA = A  + (size_t)(arow0 + srow) * 768 + scol;
  const u16* gB = Bm + (size_t)(brow0 + srow) * 768 + scol;
  const int lw = wid * 32 * 32;   // wave-uniform LDS offset (u16 units)

  f32x4 acc[4][4] = {};

  #define STAGE(asb, bsb, kb) do { \
    GLL(gA + (kb),            asb + lw); \
    GLL(gA + (kb) + 16 * 768, asb + lw + 16 * 32); \
    GLL(gB + (kb),            bsb + lw); \
    GLL(gB + (kb) + 16 * 768, bsb + lw + 16 * 32); \
  } while (0)

  #define COMPUTE(asb, bsb) do { \
    bf16x8 af[4], bfr[4]; \
    _Pragma("unroll") \
    for (int m = 0; m < 4; ++m) \
      af[m] = *(const bf16x8*)(asb + (wr * 64 + m * 16 + li) * 32 + lg * 8); \
    _Pragma("unroll") \
    for (int n = 0; n < 4; ++n) \
      bfr[n] = *(const bf16x8*)(bsb + (wc * 64 + n * 16 + li) * 32 + lg * 8); \
    _Pragma("unroll") \
    for (int m = 0; m < 4; ++m) \
      _Pragma("unroll") \
      for (int n = 0; n < 4; ++n) \
        acc[m][n] = __builtin_amdgcn_mfma_f32_16x16x32_bf16(af[m], bfr[n], acc[m][n], 0, 0, 0); \
  } while (0)

  // prologue: stage kt=0 into buf0
  STAGE(As0, Bs0, 0);
  __syncthreads();

  // 24 K-steps, 2 per loop iteration (static buffer selection)
  #pragma unroll 1
  for (int kt = 0; kt < 24; kt += 2) {
    STAGE(As1, Bs1, (kt + 1) * 32);     // prefetch odd tile
    COMPUTE(As0, Bs0);
    __syncthreads();                     // odd tile landed; buf0 free
    if (kt + 2 < 24) STAGE(As0, Bs0, (kt + 2) * 32);  // prefetch next even tile
    COMPUTE(As1, Bs1);
    __syncthreads();                     // even tile landed; buf1 free
  }
  #undef STAGE
  #undef COMPUTE

  if (EPI == 0) {
    #pragma unroll
    for (int m = 0; m < 4; ++m)
      #pragma unroll
      for (int n = 0; n < 4; ++n) {
        const int colp = brow0 + wc * 64 + n * 16 + li;
        #pragma unroll
        for (int r = 0; r < 4; ++r) {
          const int row = arow0 + wr * 64 + m * 16 + lg * 4 + r;
          if (row < M1) outF[(size_t)row * 768 + colp] = acc[m][n][r];
        }
      }
  } else {
    // rows of this thread span at most 2 batches; one div total
    const int base = arow0 + wr * 64;
    const int b0 = base / T_;
    const int rem0 = base - b0 * T_;
    #pragma unroll
    for (int n = 0; n < 4; ++n) {
      const int colp = brow0 + wc * 64 + n * 16 + li;   // [comp][head][dim] order
      const int comp = colp / 768;
      const int rem = colp - comp * 768;
      const int hh = rem >> 6, dd = rem & 63;
      #pragma unroll
      for (int m = 0; m < 4; ++m) {
        #pragma unroll
        for (int r = 0; r < 4; ++r) {
          const int off = m * 16 + lg * 4 + r;
          if (base + off >= M1) continue;
          int t = rem0 + off, b = b0;
          if (t >= T_) { b += 1; t -= T_; }
          const u16 v = f2bf(acc[m][n][r]);
          const size_t bh = (size_t)b * H_ + hh;
          if (comp == 0)      Qb[(bh * T_ + t) * 64 + dd] = v;
          else if (comp == 1) Kb[(bh * T_ + t) * 64 + dd] = v;
          else                Vt[(bh * 64 + dd) * VSTR + t] = v;
        }
      }
    }
  }
}

// ---------------- spatial attention: one block per (b,f,h), 4 waves ----------------
// keys: 0 = cls token (t=0), j in [1,196] -> t = f*196 + j. Padded key space = 224.
__global__ __launch_bounds__(256) void k_attn_sp(const u16* __restrict__ Qb,
                                                 const u16* __restrict__ Kb,
                                                 const u16* __restrict__ Vt,
                                                 u16* __restrict__ AO) {
  __shared__ u16 P[4][16 * 232];   // per-wave P tile, padded stride 232
  const int bid = blockIdx.x;
  const int h = bid % H_;
  const int f = (bid / H_) % F_;
  const int b = bid / (H_ * F_);
  const int tid = threadIdx.x;
  const int lane = tid & 63, w = tid >> 6;
  const int li = lane & 15, lg = lane >> 4;
  const size_t bh = (size_t)b * H_ + h;
  const u16* Qp = Qb + bh * T_ * 64;
  const u16* Kp = Kb + bh * T_ * 64;
  const u16* Vp = Vt + bh * 64 * VSTR;
  u16* ps = &P[w][0];

  for (int mt = w; mt < 13; mt += 4) {          // 13 m-tiles of 16 q-rows (196 valid)
    const int pp = mt * 16 + li;
    const int ppc = pp < 196 ? pp : 195;
    const size_t tq = 1 + f * 196 + ppc;
    const bf16x8 qf0 = *(const bf16x8*)(Qp + tq * 64 + lg * 8);
    const bf16x8 qf1 = *(const bf16x8*)(Qp + tq * 64 + 32 + lg * 8);

    f32x4 s[14] = {};
    #pragma unroll
    for (int n = 0; n < 14; ++n) {
      const int key = n * 16 + li;
      int tk = (key == 0) ? 0 : (f * 196 + key);
      if (tk > 3136) tk = 3136;                 // pad keys: garbage, masked below
      const u16* kp = Kp + (size_t)tk * 64;
      const bf16x8 kf0 = *(const bf16x8*)(kp + lg * 8);
      const bf16x8 kf1 = *(const bf16x8*)(kp + 32 + lg * 8);
      s[n] = __builtin_amdgcn_mfma_f32_16x16x32_bf16(qf0, kf0, s[n], 0, 0, 0);
      s[n] = __builtin_amdgcn_mfma_f32_16x16x32_bf16(qf1, kf1, s[n], 0, 0, 0);
    }

    float rsum[4];
    #pragma unroll
    for (int r = 0; r < 4; ++r) {
      float vals[14];
      float mx = -1e30f;
      #pragma unroll
      for (int n = 0; n < 14; ++n) {
        const int key = n * 16 + li;
        float sv = s[n][r] * 0.125f;
        vals[n] = (key < 197) ? sv : -1e30f;
        mx = fmaxf(mx, vals[n]);
      }
      #pragma unroll
      for (int msk = 1; msk < 16; msk <<= 1) mx = fmaxf(mx, __shfl_xor(mx, msk));
      float sum = 0.f;
      #pragma unroll
      for (int n = 0; n < 14; ++n) {
        const int key = n * 16 + li;
        float p = (key < 197) ? __expf(vals[n] - mx) : 0.f;
        sum += p;
        ps[(lg * 4 + r) * 232 + key] = f2bf(p);
      }
      #pragma unroll
      for (int msk = 1; msk < 16; msk <<= 1) sum += __shfl_xor(sum, msk);
      rsum[r] = sum;
    }

    f32x4 o[4] = {};
    #pragma unroll
    for (int ks = 0; ks < 7; ++ks) {            // K = 224 padded keys
      const bf16x8 pf = *(const bf16x8*)(ps + li * 232 + ks * 32 + lg * 8);
      const int keyb = ks * 32 + lg * 8;
      #pragma unroll
      for (int n = 0; n < 4; ++n) {
        const int d = n * 16 + li;
        const u16* vp = Vp + (size_t)d * VSTR + f * 196 + keyb;  // 8B aligned
        u16x4 va = *(const u16x4*)vp;
        u16x4 vb2 = *(const u16x4*)(vp + 4);
        if (keyb == 0) va[0] = Vp[(size_t)d * VSTR];             // patch cls (t=0)
        u16x8 uv = { va[0], va[1], va[2], va[3], vb2[0], vb2[1], vb2[2], vb2[3] };
        const bf16x8 vf = __builtin_bit_cast(bf16x8, uv);
        o[n] = __builtin_amdgcn_mfma_f32_16x16x32_bf16(pf, vf, o[n], 0, 0, 0);
      }
    }

    #pragma unroll
    for (int n = 0; n < 4; ++n) {
      const int d = n * 16 + li;
      #pragma unroll
      for (int r = 0; r < 4; ++r) {
        const int ppo = mt * 16 + lg * 4 + r;
        if (ppo < 196) {
          const size_t t = 1 + (size_t)f * 196 + ppo;
          AO[((size_t)b * T_ + t) * 768 + h * 64 + d] = f2bf(o[n][r] / rsum[r]);
        }
      }
    }
  }
}

// ---------------- cls-token attention: one block per (b,h), full 3137-key softmax ----------------
__global__ __launch_bounds__(256) void k_attn_cls(const u16* __restrict__ Qb,
                                                  const u16* __restrict__ Kb,
                                                  const u16* __restrict__ Vt,
                                                  u16* __restrict__ AO) {
  __shared__ float qs[64];
  __shared__ float sv[T_];
  __shared__ float red[8];
  const int bid = blockIdx.x;
  const int h = bid % H_;
  const int b = bid / H_;
  const size_t bh = (size_t)b * H_ + h;
  const u16* Qp = Qb + bh * T_ * 64;
  const u16* Kp = Kb + bh * T_ * 64;
  const u16* Vp = Vt + bh * 64 * VSTR;
  const int tid = threadIdx.x;
  const int lane = tid & 63, w = tid >> 6;

  if (tid < 64) qs[tid] = b2f(Qp[tid]);
  __syncthreads();

  float lmax = -1e30f;
  for (int j = tid; j < T_; j += 256) {
    const u16* kp = Kp + (size_t)j * 64;
    float acc = 0.f;
    #pragma unroll
    for (int d0 = 0; d0 < 64; d0 += 8) {
      u16x8 kv = *(const u16x8*)(kp + d0);
      #pragma unroll
      for (int e = 0; e < 8; ++e) acc += qs[d0 + e] * b2f(kv[e]);
    }
    acc *= 0.125f;
    sv[j] = acc;
    lmax = fmaxf(lmax, acc);
  }
  #pragma unroll
  for (int msk = 32; msk; msk >>= 1) lmax = fmaxf(lmax, __shfl_xor(lmax, msk));
  if (lane == 0) red[w] = lmax;
  __syncthreads();
  const float bmax = fmaxf(fmaxf(red[0], red[1]), fmaxf(red[2], red[3]));

  float lsum = 0.f;
  for (int j = tid; j < T_; j += 256) {
    float p = __expf(sv[j] - bmax);
    sv[j] = p;
    lsum += p;
  }
  #pragma unroll
  for (int msk = 32; msk; msk >>= 1) lsum += __shfl_xor(lsum, msk);
  __syncthreads();
  if (lane == 0) red[w] = lsum;
  __syncthreads();
  const float bsum = red[0] + red[1] + red[2] + red[3];

  const int d = tid >> 2, q4 = tid & 3;
  const u16* vp = Vp + (size_t)d * VSTR;
  float a = 0.f;
  for (int j = q4; j < T_; j += 4) a += sv[j] * b2f(vp[j]);
  a += __shfl_xor(a, 1);
  a += __shfl_xor(a, 2);
  if (q4 == 0) AO[(size_t)b * T_ * 768 + h * 64 + d] = f2bf(a / bsum);
}

// ---------------- launch ----------------
extern "C" void kernel_launch(void* const* d_in, const int* in_sizes, int n_in,
                              void* d_out, int out_size, void* d_ws, size_t ws_size,
                              hipStream_t stream) {
  const float* x    = (const float*)d_in[0];
  const float* Wqkv = (const float*)d_in[1];
  const float* W0   = (const float*)d_in[2];
  float* out = (float*)d_out;
  char* ws = (char*)d_ws;

  // workspace layout (bytes)
  u16* xb    = (u16*)(ws);                  // MPAD*768*2      = 38,731,776 ; later reused as AO
  u16* wqkvT = (u16*)(ws + 38731776);       // 2304*768*2      =  3,538,944
  u16* w0T   = (u16*)(ws + 42270720);       // 768*768*2       =  1,179,648
  u16* Qb    = (u16*)(ws + 43450368);       // 96*3137*64*2    = 38,547,456
  u16* Kb    = (u16*)(ws + 81997824);       // same
  u16* Vt    = (u16*)(ws + 120545280);      // 96*64*3200*2    = 39,321,600  (end 159,866,880)
  u16* AO = xb;                             // xb is dead after GEMM1

  k_cvt_x<<<dim3(18822), dim3(256), 0, stream>>>(x, xb, (M1 * D_) / 4);
  k_transpose<<<dim3(72, 24), dim3(32, 8), 0, stream>>>(Wqkv, wqkvT, 768, 2304, 1);
  k_transpose<<<dim3(24, 24), dim3(32, 8), 0, stream>>>(W0, w0T, 768, 768, 0);
  k_gemm<1><<<dim3(18, 197), dim3(256), 0, stream>>>(xb, wqkvT, nullptr, Qb, Kb, Vt);
  k_attn_sp<<<dim3(1536), dim3(256), 0, stream>>>(Qb, Kb, Vt, AO);
  k_attn_cls<<<dim3(96), dim3(256), 0, stream>>>(Qb, Kb, Vt, AO);
  k_gemm<0><<<dim3(6, 197), dim3(256), 0, stream>>>(AO, w0T, out, nullptr, nullptr, nullptr);
}